// Round 10
// baseline (177.642 us; speedup 1.0000x reference)
//
#include <hip/hip_runtime.h>

// Problem constants (from reference)
constexpr int N = 2;
constexpr int C = 20;
constexpr int H = 64;
constexpr int W = 2048;          // power of two -> wrap via & (W-1)
constexpr int HW = H * W;

constexpr int BLK   = 512;       // 8 waves = 4 strips x 2 class-halves
constexpr int TILE  = 512;       // cols per block
constexpr int STRIP = 128;       // cols per wave
constexpr int ROWF4 = 34;        // float4 items per staged row (136 floats)
constexpr int ROWF  = 136;       // floats per staged row (W0-4 .. W0+131)
constexpr int RITEMS = 170;     // real float4 items per slab (5 rows)
constexpr int SLABF = 680;       // slab floats
constexpr int SLABB = 2720;      // slab bytes
// LDS = 8 waves x 3 slabs x 2720 B = 65280 B (< 64 KB static limit)
// grid = 2*64*4 = 512 blocks x 8 waves -> 4096 waves -> 16 waves/CU resident

#define GLDS16(g, l)                                                        \
    __builtin_amdgcn_global_load_lds(                                       \
        (const __attribute__((address_space(1))) void*)(g),                 \
        (__attribute__((address_space(3))) void*)(l), 16, 0, 0)

__global__ __launch_bounds__(BLK, 4)   // 4 waves/SIMD -> VGPR cap 128
void lcl_xyz_kernel(const float* __restrict__ xyz,
                    const float* __restrict__ softmax,
                    const int* __restrict__ mask,
                    float* __restrict__ out) {
    __shared__ __align__(16) float lds[8 * 3 * SLABF];   // 65280 B

    const int t  = threadIdx.x;
    const int l  = t & 63;                 // lane
    const int wv = t >> 6;                 // wave 0..7
    const int sg = wv & 3;                 // strip index
    const int cb = (wv >> 2) * 10;         // class base: 0 or 10

    // XCD-contiguous strip swizzle: XCD (bid%8) owns 64 consecutive work ids
    // = 16 contiguous (n*64+h) rows per XCD L2.
    const int bid  = blockIdx.x;
    const int work = (bid & 7) * 64 + (bid >> 3);   // bijective over [0,512)
    const int nh   = work >> 2;
    const int bw   = work & 3;
    const int n    = nh >> 6;
    const int h    = nh & 63;
    const int W0   = bw * TILE + STRIP * sg;        // wave strip base col
    const int w    = W0 + 2 * l;                    // thread's first output col

    int  rowoff[5];
    bool hv[5];
    #pragma unroll
    for (int r = 0; r < 5; ++r) {
        int hh = h - 2 + r;
        hv[r] = (unsigned)hh < (unsigned)H;
        rowoff[r] = min(max(hh, 0), H - 1) * W;
    }

    const float* xb  = xyz + (size_t)(n * 3 + 0) * HW;
    const float* yb  = xyz + (size_t)(n * 3 + 1) * HW;
    const float* zb  = xyz + (size_t)(n * 3 + 2) * HW;
    const int*   mb  = mask + (size_t)n * HW;
    const float* smb = softmax + (size_t)n * C * HW;

    // ---- Weight phase: direct global float2 loads (one-time, no LDS, no sync).
    //      Duplicated across the two class-halves (L1-hit; buys 2x occupancy).
    const int cm = (w - 2) & (W - 1);
    const int c0 = w;
    const int cp = (w + 2) & (W - 1);

    const float2 cx2 = *(const float2*)(xb + h * W + c0);
    const float2 cy2 = *(const float2*)(yb + h * W + c0);
    const float2 cz2 = *(const float2*)(zb + h * W + c0);

    float wa[5][5], wb_[5][5];
    #pragma unroll
    for (int r = 0; r < 5; ++r) {
        float2 xm = *(const float2*)(xb + rowoff[r] + cm);
        float2 x0 = *(const float2*)(xb + rowoff[r] + c0);
        float2 xp = *(const float2*)(xb + rowoff[r] + cp);
        float2 ym = *(const float2*)(yb + rowoff[r] + cm);
        float2 y0 = *(const float2*)(yb + rowoff[r] + c0);
        float2 yp = *(const float2*)(yb + rowoff[r] + cp);
        float2 zm = *(const float2*)(zb + rowoff[r] + cm);
        float2 z0 = *(const float2*)(zb + rowoff[r] + c0);
        float2 zp = *(const float2*)(zb + rowoff[r] + cp);
        int2   km = *(const int2*)(mb + rowoff[r] + cm);
        int2   k0 = *(const int2*)(mb + rowoff[r] + c0);
        int2   kp = *(const int2*)(mb + rowoff[r] + cp);

        const float xv[6] = {xm.x, xm.y, x0.x, x0.y, xp.x, xp.y};
        const float yv[6] = {ym.x, ym.y, y0.x, y0.y, yp.x, yp.y};
        const float zv[6] = {zm.x, zm.y, z0.x, z0.y, zp.x, zp.y};
        const int   mv[6] = {km.x, km.y, k0.x, k0.y, kp.x, kp.y};

        #pragma unroll
        for (int j = 0; j < 5; ++j) {
            float dx = xv[j] - cx2.x, dy = yv[j] - cy2.x, dz = zv[j] - cz2.x;
            float d2 = dx * dx + dy * dy + dz * dz;
            wa[r][j] = (hv[r] && mv[j]) ? d2 : 1e30f;       // masked -> exp -> 0
            float ex = xv[j + 1] - cx2.y, ey = yv[j + 1] - cy2.y, ez = zv[j + 1] - cz2.y;
            float e2 = ex * ex + ey * ey + ez * ez;
            wb_[r][j] = (hv[r] && mv[j + 1]) ? e2 : 1e30f;
        }
    }
    #pragma unroll
    for (int r = 0; r < 5; ++r)
        #pragma unroll
        for (int j = 0; j < 5; ++j) {
            wa[r][j]  = __expf(-0.5f * wa[r][j]);
            wb_[r][j] = __expf(-0.5f * wb_[r][j]);
        }
    // All weight loads consumed above -> retired; vmcnt stream is now empty.

    // ---- Per-wave staging tuples: up to 3 global_load_lds per class ----
    int so0, so1, so2;
    {
        int so[3];
        #pragma unroll
        for (int i = 0; i < 3; ++i) {
            int it = l + 64 * i;
            if (it >= RITEMS) it = 0;        // only used when guarded-in anyway
            int r = it / ROWF4;
            int k = it - r * ROWF4;
            so[i] = rowoff[r] + ((W0 - 4 + 4 * k) & (W - 1));
        }
        so0 = so[0]; so1 = so[1]; so2 = so[2];
    }
    char*        ldst = (char*)lds + wv * (3 * SLABB) + l * 16;
    const float* wlds = lds + wv * (3 * SLABF);
    const int    lcol = 2 * l + 2;          // local col of leftmost tap

    // ---- Prime pipeline: classes cb..cb+2 into slabs 0..2 ----
    #pragma unroll
    for (int pc = 0; pc < 3; ++pc) {
        const float* sc = smb + (size_t)(cb + pc) * HW;
        GLDS16(sc + so0, ldst + pc * SLABB);
        GLDS16(sc + so1, ldst + pc * SLABB + 1024);
        if (l < RITEMS - 128) GLDS16(sc + so2, ldst + pc * SLABB + 2048);
    }

    float2 acc[10];

    // Per-wave step: counted vmcnt (per-wave counter -> no barrier),
    // compute class cb+K from slab K%3, then refill that slab with cb+K+3.
#define STEP(K, KLIT)                                                        \
    do {                                                                     \
        asm volatile("s_waitcnt vmcnt(" #KLIT ")" ::: "memory");             \
        const float* rw = wlds + ((K) % 3) * SLABF + lcol;                   \
        float a0 = 0.f, a1 = 0.f;                                            \
        _Pragma("unroll")                                                    \
        for (int r = 0; r < 5; ++r) {                                        \
            const float* p = rw + r * ROWF;                                  \
            float2 u0 = *(const float2*)(p);                                 \
            float2 u1 = *(const float2*)(p + 2);                             \
            float2 u2 = *(const float2*)(p + 4);                             \
            a0 = fmaf(wa[r][0], u0.x, a0);  a0 = fmaf(wa[r][1], u0.y, a0);   \
            a0 = fmaf(wa[r][2], u1.x, a0);  a0 = fmaf(wa[r][3], u1.y, a0);   \
            a0 = fmaf(wa[r][4], u2.x, a0);                                   \
            a1 = fmaf(wb_[r][0], u0.y, a1); a1 = fmaf(wb_[r][1], u1.x, a1);  \
            a1 = fmaf(wb_[r][2], u1.y, a1); a1 = fmaf(wb_[r][3], u2.x, a1);  \
            a1 = fmaf(wb_[r][4], u2.y, a1);                                  \
        }                                                                    \
        acc[K].x = a0; acc[K].y = a1;                                        \
        __builtin_amdgcn_sched_barrier(0);  /* pin refill after slab reads */\
        if ((K) + 3 < 10) {                                                  \
            const float* scn = smb + (size_t)(cb + (K) + 3) * HW;            \
            GLDS16(scn + so0, ldst + ((K) % 3) * SLABB);                     \
            GLDS16(scn + so1, ldst + ((K) % 3) * SLABB + 1024);              \
            if (l < RITEMS - 128)                                            \
                GLDS16(scn + so2, ldst + ((K) % 3) * SLABB + 2048);          \
        }                                                                    \
    } while (0)

    STEP(0, 6);  STEP(1, 6);  STEP(2, 6);  STEP(3, 6);  STEP(4, 6);
    STEP(5, 6);  STEP(6, 6);  STEP(7, 6);  STEP(8, 3);  STEP(9, 0);
#undef STEP

    // ---- Epilogue: coalesced float2 stores (10 classes) ----
    float* ob = out + (size_t)n * C * HW + (size_t)cb * HW + (size_t)h * W + w;
    #pragma unroll
    for (int k = 0; k < 10; ++k)
        *(float2*)(ob + (size_t)k * HW) = acc[k];
}

extern "C" void kernel_launch(void* const* d_in, const int* in_sizes, int n_in,
                              void* d_out, int out_size, void* d_ws, size_t ws_size,
                              hipStream_t stream) {
    const float* xyz     = (const float*)d_in[0];
    const float* softmax = (const float*)d_in[1];
    const int*   mask    = (const int*)d_in[2];
    float*       out     = (float*)d_out;

    const int grid = N * H * (W / TILE);     // 512 blocks
    lcl_xyz_kernel<<<grid, BLK, 0, stream>>>(xyz, softmax, mask, out);
}

// Round 11
// 171.848 us; speedup vs baseline: 1.0337x; 1.0337x over previous
//
#include <hip/hip_runtime.h>

// Problem constants (from reference)
constexpr int N = 2;
constexpr int C = 20;
constexpr int H = 64;
constexpr int W = 2048;          // power of two -> wrap via & (W-1)
constexpr int HW = H * W;

constexpr int BLK   = 256;       // 4 waves = 2 strips x {even,odd} class streams
constexpr int TILE  = 256;       // cols per block
constexpr int STRIP = 128;       // cols per wave
constexpr int ROWF4 = 34;        // float4 items per staged row
constexpr int ROWF  = 136;       // floats per staged row (W0-4 .. W0+131)
constexpr int RITEMS = 170;      // real float4 items per slab (5 rows)
constexpr int SLABF = 680;       // slab floats
constexpr int SLABB = 2720;      // slab bytes
// LDS = 4 waves x 3 slabs x 2720 B = 32640 B -> 4 blocks/CU -> 16 waves/CU
// grid = 2*64*8 = 1024 blocks = exactly 4 blocks/CU resident

#define GLDS16(g, l)                                                        \
    __builtin_amdgcn_global_load_lds(                                       \
        (const __attribute__((address_space(1))) void*)(g),                 \
        (__attribute__((address_space(3))) void*)(l), 16, 0, 0)

__global__ __launch_bounds__(BLK, 4)   // 4 waves/EU -> VGPR cap 128
void lcl_xyz_kernel(const float* __restrict__ xyz,
                    const float* __restrict__ softmax,
                    const int* __restrict__ mask,
                    float* __restrict__ out) {
    __shared__ __align__(16) float lds[4 * 3 * SLABF];   // 32640 B

    const int t  = threadIdx.x;
    const int l  = t & 63;                 // lane
    const int wv = t >> 6;                 // wave 0..3
    const int sg = wv >> 1;                // strip index 0..1
    const int p  = wv & 1;                 // class parity: classes p, p+2, ..., p+18

    // XCD-contiguous strip swizzle (R6's measured-good scheme for 1024 blocks):
    // XCD (bid%8) owns 128 consecutive work ids = 16 contiguous (n*64+h) rows.
    const int bid  = blockIdx.x;
    const int work = (bid & 7) * 128 + (bid >> 3);   // bijective over [0,1024)
    const int nh   = work >> 3;
    const int bw   = work & 7;
    const int n    = nh >> 6;
    const int h    = nh & 63;
    const int W0   = bw * TILE + STRIP * sg;         // wave strip base col
    const int w    = W0 + 2 * l;                     // thread's first output col

    int  rowoff[5];
    bool hv[5];
    #pragma unroll
    for (int r = 0; r < 5; ++r) {
        int hh = h - 2 + r;
        hv[r] = (unsigned)hh < (unsigned)H;
        rowoff[r] = min(max(hh, 0), H - 1) * W;
    }

    const float* xb  = xyz + (size_t)(n * 3 + 0) * HW;
    const float* yb  = xyz + (size_t)(n * 3 + 1) * HW;
    const float* zb  = xyz + (size_t)(n * 3 + 2) * HW;
    const int*   mb  = mask + (size_t)n * HW;
    const float* smb = softmax + (size_t)n * C * HW;

    // ---- Weight phase: direct global float2 loads (one-time, no LDS, no sync).
    //      Duplicated across the two parity waves of a strip (L1-shared).
    const int cm = (w - 2) & (W - 1);
    const int c0 = w;
    const int cp = (w + 2) & (W - 1);

    const float2 cx2 = *(const float2*)(xb + h * W + c0);
    const float2 cy2 = *(const float2*)(yb + h * W + c0);
    const float2 cz2 = *(const float2*)(zb + h * W + c0);

    float wa[5][5], wb_[5][5];
    #pragma unroll
    for (int r = 0; r < 5; ++r) {
        float2 xm = *(const float2*)(xb + rowoff[r] + cm);
        float2 x0 = *(const float2*)(xb + rowoff[r] + c0);
        float2 xp = *(const float2*)(xb + rowoff[r] + cp);
        float2 ym = *(const float2*)(yb + rowoff[r] + cm);
        float2 y0 = *(const float2*)(yb + rowoff[r] + c0);
        float2 yp = *(const float2*)(yb + rowoff[r] + cp);
        float2 zm = *(const float2*)(zb + rowoff[r] + cm);
        float2 z0 = *(const float2*)(zb + rowoff[r] + c0);
        float2 zp = *(const float2*)(zb + rowoff[r] + cp);
        int2   km = *(const int2*)(mb + rowoff[r] + cm);
        int2   k0 = *(const int2*)(mb + rowoff[r] + c0);
        int2   kp = *(const int2*)(mb + rowoff[r] + cp);

        const float xv[6] = {xm.x, xm.y, x0.x, x0.y, xp.x, xp.y};
        const float yv[6] = {ym.x, ym.y, y0.x, y0.y, yp.x, yp.y};
        const float zv[6] = {zm.x, zm.y, z0.x, z0.y, zp.x, zp.y};
        const int   mv[6] = {km.x, km.y, k0.x, k0.y, kp.x, kp.y};

        #pragma unroll
        for (int j = 0; j < 5; ++j) {
            float dx = xv[j] - cx2.x, dy = yv[j] - cy2.x, dz = zv[j] - cz2.x;
            float d2 = dx * dx + dy * dy + dz * dz;
            wa[r][j] = (hv[r] && mv[j]) ? d2 : 1e30f;       // masked -> exp -> 0
            float ex = xv[j + 1] - cx2.y, ey = yv[j + 1] - cy2.y, ez = zv[j + 1] - cz2.y;
            float e2 = ex * ex + ey * ey + ez * ez;
            wb_[r][j] = (hv[r] && mv[j + 1]) ? e2 : 1e30f;
        }
    }
    #pragma unroll
    for (int r = 0; r < 5; ++r)
        #pragma unroll
        for (int j = 0; j < 5; ++j) {
            wa[r][j]  = __expf(-0.5f * wa[r][j]);
            wb_[r][j] = __expf(-0.5f * wb_[r][j]);
        }
    // All weight loads consumed above -> retired; vmcnt stream now holds only slabs.

    // ---- Per-wave staging tuples: 3 global_load_lds per class ----
    int so0, so1, so2;
    {
        int so[3];
        #pragma unroll
        for (int i = 0; i < 3; ++i) {
            int it = l + 64 * i;
            if (it >= RITEMS) it = 0;        // only reachable for guarded-out lanes
            int r = it / ROWF4;
            int k = it - r * ROWF4;
            so[i] = rowoff[r] + ((W0 - 4 + 4 * k) & (W - 1));
        }
        so0 = so[0]; so1 = so[1]; so2 = so[2];
    }
    char*        ldst = (char*)lds + wv * (3 * SLABB) + l * 16;
    const float* wlds = lds + wv * (3 * SLABF);
    const int    lcol = 2 * l + 2;          // local col of leftmost tap

    // ---- Prime pipeline: classes p, p+2, p+4 into slabs 0..2 (9 loads) ----
    #pragma unroll
    for (int pc = 0; pc < 3; ++pc) {
        const float* sc = smb + (size_t)(p + 2 * pc) * HW;
        GLDS16(sc + so0, ldst + pc * SLABB);
        GLDS16(sc + so1, ldst + pc * SLABB + 1024);
        if (l < RITEMS - 128) GLDS16(sc + so2, ldst + pc * SLABB + 2048);
    }

    float2 acc[10];

    // Per-wave step: counted vmcnt (wave-private slabs -> no memory barrier),
    // compute class p+2K from slab K%3, refill with class p+2(K+3), then a BARE
    // s_barrier as a pacing device only (bounds intra-block class drift; no
    // vmcnt drain, nothing crosses it).
#define STEP(K, KLIT)                                                        \
    do {                                                                     \
        asm volatile("s_waitcnt vmcnt(" #KLIT ")" ::: "memory");             \
        const float* rw = wlds + ((K) % 3) * SLABF + lcol;                   \
        float a0 = 0.f, a1 = 0.f;                                            \
        _Pragma("unroll")                                                    \
        for (int r = 0; r < 5; ++r) {                                        \
            const float* q = rw + r * ROWF;                                  \
            float2 u0 = *(const float2*)(q);                                 \
            float2 u1 = *(const float2*)(q + 2);                             \
            float2 u2 = *(const float2*)(q + 4);                             \
            a0 = fmaf(wa[r][0], u0.x, a0);  a0 = fmaf(wa[r][1], u0.y, a0);   \
            a0 = fmaf(wa[r][2], u1.x, a0);  a0 = fmaf(wa[r][3], u1.y, a0);   \
            a0 = fmaf(wa[r][4], u2.x, a0);                                   \
            a1 = fmaf(wb_[r][0], u0.y, a1); a1 = fmaf(wb_[r][1], u1.x, a1);  \
            a1 = fmaf(wb_[r][2], u1.y, a1); a1 = fmaf(wb_[r][3], u2.x, a1);  \
            a1 = fmaf(wb_[r][4], u2.y, a1);                                  \
        }                                                                    \
        acc[K].x = a0; acc[K].y = a1;                                        \
        __builtin_amdgcn_sched_barrier(0);  /* pin refill after slab reads */\
        if ((K) + 3 < 10) {                                                  \
            const float* scn = smb + (size_t)(p + 2 * ((K) + 3)) * HW;       \
            GLDS16(scn + so0, ldst + ((K) % 3) * SLABB);                     \
            GLDS16(scn + so1, ldst + ((K) % 3) * SLABB + 1024);              \
            if (l < RITEMS - 128)                                            \
                GLDS16(scn + so2, ldst + ((K) % 3) * SLABB + 2048);          \
        }                                                                    \
        __builtin_amdgcn_s_barrier();       /* pacing only */                \
    } while (0)

    STEP(0, 6);  STEP(1, 6);  STEP(2, 6);  STEP(3, 6);  STEP(4, 6);
    STEP(5, 6);  STEP(6, 6);  STEP(7, 6);  STEP(8, 3);  STEP(9, 0);
#undef STEP

    // ---- Epilogue: coalesced float2 stores (classes p, p+2, ..., p+18) ----
    float* ob = out + (size_t)n * C * HW + (size_t)h * W + w;
    #pragma unroll
    for (int k = 0; k < 10; ++k)
        *(float2*)(ob + (size_t)(p + 2 * k) * HW) = acc[k];
}

extern "C" void kernel_launch(void* const* d_in, const int* in_sizes, int n_in,
                              void* d_out, int out_size, void* d_ws, size_t ws_size,
                              hipStream_t stream) {
    const float* xyz     = (const float*)d_in[0];
    const float* softmax = (const float*)d_in[1];
    const int*   mask    = (const int*)d_in[2];
    float*       out     = (float*)d_out;

    const int grid = N * H * (W / TILE);     // 2*64*8 = 1024 blocks
    lcl_xyz_kernel<<<grid, BLK, 0, stream>>>(xyz, softmax, mask, out);
}